// Round 10
// baseline (402.981 us; speedup 1.0000x reference)
//
#include <hip/hip_runtime.h>

// OrthogonalAddTSU: sequential scan over S steps, carry h:(B,H).
// Per step: cos = <h,s>/max(|h||s|,eps); h = clip(h + (s - h*cos)*m, -1, 1).
// B=64, H=1024, S=512.
//
// Round-14: dual-batch fused consumer (grid 32, 2 batches per block).
//  - r13 post-mortem: conflicts -66% but time -1.5% -> LDS exonerated.
//    Wall/step = issue(~190cy) + ~415cy intrinsic chain stall (tree ->
//    6-stage DPP butterfly -> readlane -> rsq -> update). A wave issues
//    in order: nothing else in its stream to fill the stall.
//  - Fix: interleave TWO independent recurrences in one consumer wave.
//    Each step: A/B trees interleaved, 6-chain interleaved butterfly
//    (dependent DPPs 6 instrs apart), 2 rsq tails, 2 conditional updates.
//    B's issue fills A's stalls. Expected ~420-480cy/step for BOTH.
//  - Window = 8 steps; LDS = 4 bufs (2 batches x 2 parity) x 32896B =
//    131584B (same as r13). Stride 4112B kept (16B-aligned b128; producer
//    writes 2 lanes/bank = free minimum).
//  - Producers (waves 1-3): per window stage both batches' 8-step tiles:
//    64 chunks (32 rows x 8 steps each), wave w takes cc=3k+(w-1) -> 22
//    loads + 88 ds_write_b32 (same counts as r13). Loads: 32 rows x 32B
//    (half-line; other half next window, L2-resident).
//  - Consumer waits: ONE lgkmcnt(0) per step (prefetch T+1 issued right
//    after the wait -> full compute-time distance). No DS op crosses a
//    barrier. Barriers 65/65. No OOB anywhere (no tail garbage loads).
//  - All primitives r13-proven: volatile asm loads/ds, pure pk asm, DPP
//    butterfly, readlane. No ds_swizzle, no cross-wave partials.

#define NB 32
#define NH 1024
#define NS 512

#define STRB 4112u             // step stride bytes (16*257)
#define BUFB 32896u            // 8 * 4112 per buffer

typedef float v4f __attribute__((ext_vector_type(4)));
typedef float v2f __attribute__((ext_vector_type(2)));

template <int N> struct ic { static constexpr int value = N; };

template <int CTRL>
__device__ __forceinline__ float dpp_add(float x) {
  int s = __builtin_amdgcn_update_dpp(0, __builtin_bit_cast(int, x), CTRL, 0xf,
                                      0xf, true);
  return x + __builtin_bit_cast(float, s);
}

__device__ __forceinline__ float readlane_f(float v, int lane) {
  return __builtin_bit_cast(
      float, __builtin_amdgcn_readlane(__builtin_bit_cast(int, v), lane));
}

// 6 interleaved 6-stage butterflies; broadcast lane63 totals.
__device__ __forceinline__ void wave_red6(float& a, float& b, float& c,
                                          float& d, float& e, float& f) {
  a = dpp_add<0x111>(a); b = dpp_add<0x111>(b); c = dpp_add<0x111>(c);
  d = dpp_add<0x111>(d); e = dpp_add<0x111>(e); f = dpp_add<0x111>(f);
  a = dpp_add<0x112>(a); b = dpp_add<0x112>(b); c = dpp_add<0x112>(c);
  d = dpp_add<0x112>(d); e = dpp_add<0x112>(e); f = dpp_add<0x112>(f);
  a = dpp_add<0x114>(a); b = dpp_add<0x114>(b); c = dpp_add<0x114>(c);
  d = dpp_add<0x114>(d); e = dpp_add<0x114>(e); f = dpp_add<0x114>(f);
  a = dpp_add<0x118>(a); b = dpp_add<0x118>(b); c = dpp_add<0x118>(c);
  d = dpp_add<0x118>(d); e = dpp_add<0x118>(e); f = dpp_add<0x118>(f);
  a = dpp_add<0x142>(a); b = dpp_add<0x142>(b); c = dpp_add<0x142>(c);
  d = dpp_add<0x142>(d); e = dpp_add<0x142>(e); f = dpp_add<0x142>(f);
  a = dpp_add<0x143>(a); b = dpp_add<0x143>(b); c = dpp_add<0x143>(c);
  d = dpp_add<0x143>(d); e = dpp_add<0x143>(e); f = dpp_add<0x143>(f);
  a = readlane_f(a, 63); b = readlane_f(b, 63); c = readlane_f(c, 63);
  d = readlane_f(d, 63); e = readlane_f(e, 63); f = readlane_f(f, 63);
}

#define GLD4(dst, p) \
  asm volatile("global_load_dwordx4 %0, %1, off" : "=v"(dst) : "v"(p))
#define GLD4O(dst, p, OFF) \
  asm volatile("global_load_dwordx4 %0, %1, off offset:" OFF \
               : "=v"(dst) : "v"(p))
#define GLD1(dst, p) \
  asm volatile("global_load_dword %0, %1, off" : "=v"(dst) : "v"(p))

template <int IMM>
__device__ __forceinline__ void dsr128(v4f& d, unsigned a) {
  asm volatile("ds_read_b128 %[d], %[a] offset:%[o]"
               : [d] "=v"(d)
               : [a] "v"(a), [o] "n"(IMM));
}
template <int IMM>
__device__ __forceinline__ void dsw32(unsigned a, float v) {
  asm volatile("ds_write_b32 %[a], %[v] offset:%[o]" ::[a] "v"(a), [v] "v"(v),
               [o] "n"(IMM));
}

// Packed fp32 math (pure: compiler may schedule freely; real dataflow).
__device__ __forceinline__ v2f pk_fma(v2f a, v2f b, v2f c) {
  v2f d;
  asm("v_pk_fma_f32 %0, %1, %2, %3" : "=v"(d) : "v"(a), "v"(b), "v"(c));
  return d;
}
__device__ __forceinline__ v2f pk_mul(v2f a, v2f b) {
  v2f d;
  asm("v_pk_mul_f32 %0, %1, %2" : "=v"(d) : "v"(a), "v"(b));
  return d;
}
__device__ __forceinline__ v2f pk_add(v2f a, v2f b) {
  v2f d;
  asm("v_pk_add_f32 %0, %1, %2" : "=v"(d) : "v"(a), "v"(b));
  return d;
}

// read step T of a tile buffer into 4 v4f
template <int T>
__device__ __forceinline__ void read_step(unsigned rb, v4f (&sv)[4]) {
  dsr128<(int)(T * STRB) + 0>(sv[0], rb);
  dsr128<(int)(T * STRB) + 1024>(sv[1], rb);
  dsr128<(int)(T * STRB) + 2048>(sv[2], rb);
  dsr128<(int)(T * STRB) + 3072>(sv[3], rb);
}

#define LGK0AB(a, b)                                                   \
  asm volatile("s_waitcnt lgkmcnt(0)"                                  \
               : "+v"((a)[0]), "+v"((a)[1]), "+v"((a)[2]),             \
                 "+v"((a)[3]), "+v"((b)[0]), "+v"((b)[1]),             \
                 "+v"((b)[2]), "+v"((b)[3]))

__global__ __launch_bounds__(256, 1) void otsu_scan_kernel(
    const float* __restrict__ tree,   // (B,H)
    const float* __restrict__ seq,    // (B,H,S)
    const float* __restrict__ mask,   // (B,S)
    float* __restrict__ out) {        // (B,H)
  // 4 buffers: [batchA p0, batchA p1, batchB p0, batchB p1] x 32896 B
  __shared__ float lds[4 * 8 * 1028];  // 131584 B
  const int tid = threadIdx.x;
  const int w = tid >> 6;   // wave 0..3 (wave-uniform)
  const int l = tid & 63;   // lane
  const int bA = 2 * blockIdx.x;
  const int bB = bA + 1;
  const unsigned lb = (unsigned)(unsigned long long)(&lds[0]);

  if (w == 0) {
    // ============================ CONSUMER ============================
    // lane l owns h[4l + 256m + {0..3}] for BOTH batches.
    const float* hrA = tree + bA * NH + 4 * l;
    const float* hrB = tree + bB * NH + 4 * l;
    v4f hA0, hA1, hA2v, hA3, hB0, hB1, hB2v, hB3;
    GLD4(hA0, hrA);
    GLD4O(hA1, hrA, "1024");
    GLD4O(hA2v, hrA, "2048");
    GLD4O(hA3, hrA, "3072");
    GLD4(hB0, hrB);
    GLD4O(hB1, hrB, "1024");
    GLD4O(hB2v, hrB, "2048");
    GLD4O(hB3, hrB, "3072");
    float mA[8], mB[8];
    {
      const float* mpA = mask + bA * NS + l;
      const float* mpB = mask + bB * NS + l;
#pragma unroll
      for (int i = 0; i < 8; ++i) GLD1(mA[i], mpA + 64 * i);
#pragma unroll
      for (int i = 0; i < 8; ++i) GLD1(mB[i], mpB + 64 * i);
    }
    asm volatile("s_waitcnt vmcnt(0)"
                 : "+v"(hA0), "+v"(hA1), "+v"(hA2v), "+v"(hA3), "+v"(hB0),
                   "+v"(hB1), "+v"(hB2v), "+v"(hB3));
    asm volatile("s_waitcnt vmcnt(0)"
                 : "+v"(mA[0]), "+v"(mA[1]), "+v"(mA[2]), "+v"(mA[3]),
                   "+v"(mA[4]), "+v"(mA[5]), "+v"(mA[6]), "+v"(mA[7]),
                   "+v"(mB[0]), "+v"(mB[1]), "+v"(mB[2]), "+v"(mB[3]),
                   "+v"(mB[4]), "+v"(mB[5]), "+v"(mB[6]), "+v"(mB[7]));

    v2f hA[8], hB[8];
    hA[0] = v2f{hA0[0], hA0[1]}; hA[1] = v2f{hA0[2], hA0[3]};
    hA[2] = v2f{hA1[0], hA1[1]}; hA[3] = v2f{hA1[2], hA1[3]};
    hA[4] = v2f{hA2v[0], hA2v[1]}; hA[5] = v2f{hA2v[2], hA2v[3]};
    hA[6] = v2f{hA3[0], hA3[1]}; hA[7] = v2f{hA3[2], hA3[3]};
    hB[0] = v2f{hB0[0], hB0[1]}; hB[1] = v2f{hB0[2], hB0[3]};
    hB[2] = v2f{hB1[0], hB1[1]}; hB[3] = v2f{hB1[2], hB1[3]};
    hB[4] = v2f{hB2v[0], hB2v[1]}; hB[5] = v2f{hB2v[2], hB2v[3]};
    hB[6] = v2f{hB3[0], hB3[1]}; hB[7] = v2f{hB3[2], hB3[3]};

    unsigned mbitsA = 0u, mbitsB = 0u;
#pragma unroll
    for (int i = 0; i < 8; ++i) {
      if (mA[i] != 0.0f) mbitsA |= (1u << i);
      if (mB[i] != 0.0f) mbitsB |= (1u << i);
    }

    // t==0, m==0: clip still applies (per batch)
    if (!(__builtin_amdgcn_readlane((int)mbitsA, 0) & 1)) {
#pragma unroll
      for (int p = 0; p < 8; ++p) {
        hA[p].x = __builtin_amdgcn_fmed3f(hA[p].x, -1.0f, 1.0f);
        hA[p].y = __builtin_amdgcn_fmed3f(hA[p].y, -1.0f, 1.0f);
      }
    }
    if (!(__builtin_amdgcn_readlane((int)mbitsB, 0) & 1)) {
#pragma unroll
      for (int p = 0; p < 8; ++p) {
        hB[p].x = __builtin_amdgcn_fmed3f(hB[p].x, -1.0f, 1.0f);
        hB[p].y = __builtin_amdgcn_fmed3f(hB[p].y, -1.0f, 1.0f);
      }
    }

    const unsigned rbA0 = lb + 16u * (unsigned)l;           // batch A bufs
    const unsigned rbB0 = rbA0 + 2u * BUFB;                 // batch B bufs
    v4f svA[2][4], svB[2][4];

    asm volatile("s_barrier" ::: "memory");  // barrier #0: tile 0 staged

#pragma unroll 1
    for (int g = 0; g < 64; ++g) {
      const int lbase = 8 * (g & 7);
      const int msh = g >> 3;
      const unsigned po = (g & 1) ? BUFB : 0u;
      const unsigned rbA = rbA0 + po;
      const unsigned rbB = rbB0 + po;

      read_step<0>(rbA, svA[0]);  // window preamble: step 0, both batches
      read_step<0>(rbB, svB[0]);

      auto step = [&](auto sc) {
        constexpr int T = decltype(sc)::value;
        LGK0AB(svA[T & 1], svB[T & 1]);
        if constexpr (T < 7) {  // prefetch next step (full-compute distance)
          read_step<T + 1>(rbA, svA[(T + 1) & 1]);
          read_step<T + 1>(rbB, svB[(T + 1) & 1]);
        }
        const v4f a0 = svA[T & 1][0], a1 = svA[T & 1][1],
                  a2 = svA[T & 1][2], a3 = svA[T & 1][3];
        const v4f b0 = svB[T & 1][0], b1 = svB[T & 1][1],
                  b2 = svB[T & 1][2], b3 = svB[T & 1][3];
        v2f sa[8], sb[8];
        sa[0] = v2f{a0[0], a0[1]}; sa[1] = v2f{a0[2], a0[3]};
        sa[2] = v2f{a1[0], a1[1]}; sa[3] = v2f{a1[2], a1[3]};
        sa[4] = v2f{a2[0], a2[1]}; sa[5] = v2f{a2[2], a2[3]};
        sa[6] = v2f{a3[0], a3[1]}; sa[7] = v2f{a3[2], a3[3]};
        sb[0] = v2f{b0[0], b0[1]}; sb[1] = v2f{b0[2], b0[3]};
        sb[2] = v2f{b1[0], b1[1]}; sb[3] = v2f{b1[2], b1[3]};
        sb[4] = v2f{b2[0], b2[1]}; sb[5] = v2f{b2[2], b2[3]};
        sb[6] = v2f{b3[0], b3[1]}; sb[7] = v2f{b3[2], b3[3]};
        // interleaved product trees (A/B alternate -> fills chain stalls)
        v2f dA0 = pk_mul(hA[0], sa[0]), dB0 = pk_mul(hB[0], sb[0]);
        v2f dA1 = pk_mul(hA[1], sa[1]), dB1 = pk_mul(hB[1], sb[1]);
        v2f dA2 = pk_mul(hA[2], sa[2]), dB2 = pk_mul(hB[2], sb[2]);
        v2f dA3 = pk_mul(hA[3], sa[3]), dB3 = pk_mul(hB[3], sb[3]);
        v2f eA0 = pk_mul(hA[0], hA[0]), eB0 = pk_mul(hB[0], hB[0]);
        v2f eA1 = pk_mul(hA[1], hA[1]), eB1 = pk_mul(hB[1], hB[1]);
        v2f eA2 = pk_mul(hA[2], hA[2]), eB2 = pk_mul(hB[2], hB[2]);
        v2f eA3 = pk_mul(hA[3], hA[3]), eB3 = pk_mul(hB[3], hB[3]);
        v2f fA0 = pk_mul(sa[0], sa[0]), fB0 = pk_mul(sb[0], sb[0]);
        v2f fA1 = pk_mul(sa[1], sa[1]), fB1 = pk_mul(sb[1], sb[1]);
        v2f fA2 = pk_mul(sa[2], sa[2]), fB2 = pk_mul(sb[2], sb[2]);
        v2f fA3 = pk_mul(sa[3], sa[3]), fB3 = pk_mul(sb[3], sb[3]);
        dA0 = pk_fma(hA[4], sa[4], dA0); dB0 = pk_fma(hB[4], sb[4], dB0);
        dA1 = pk_fma(hA[5], sa[5], dA1); dB1 = pk_fma(hB[5], sb[5], dB1);
        dA2 = pk_fma(hA[6], sa[6], dA2); dB2 = pk_fma(hB[6], sb[6], dB2);
        dA3 = pk_fma(hA[7], sa[7], dA3); dB3 = pk_fma(hB[7], sb[7], dB3);
        eA0 = pk_fma(hA[4], hA[4], eA0); eB0 = pk_fma(hB[4], hB[4], eB0);
        eA1 = pk_fma(hA[5], hA[5], eA1); eB1 = pk_fma(hB[5], hB[5], eB1);
        eA2 = pk_fma(hA[6], hA[6], eA2); eB2 = pk_fma(hB[6], hB[6], eB2);
        eA3 = pk_fma(hA[7], hA[7], eA3); eB3 = pk_fma(hB[7], hB[7], eB3);
        fA0 = pk_fma(sa[4], sa[4], fA0); fB0 = pk_fma(sb[4], sb[4], fB0);
        fA1 = pk_fma(sa[5], sa[5], fA1); fB1 = pk_fma(sb[5], sb[5], fB1);
        fA2 = pk_fma(sa[6], sa[6], fA2); fB2 = pk_fma(sb[6], sb[6], fB2);
        fA3 = pk_fma(sa[7], sa[7], fA3); fB3 = pk_fma(sb[7], sb[7], fB3);
        v2f DA = pk_add(pk_add(dA0, dA1), pk_add(dA2, dA3));
        v2f DB = pk_add(pk_add(dB0, dB1), pk_add(dB2, dB3));
        v2f EA = pk_add(pk_add(eA0, eA1), pk_add(eA2, eA3));
        v2f EB = pk_add(pk_add(eB0, eB1), pk_add(eB2, eB3));
        v2f FA = pk_add(pk_add(fA0, fA1), pk_add(fA2, fA3));
        v2f FB = pk_add(pk_add(fB0, fB1), pk_add(fB2, fB3));
        float pdA = DA.x + DA.y, phA = EA.x + EA.y, psA = FA.x + FA.y;
        float pdB = DB.x + DB.y, phB = EB.x + EB.y, psB = FB.x + FB.y;
        wave_red6(pdA, phA, psA, pdB, phB, psB);
        const float qA = fmaxf(phA * psA, 1e-16f);  // denom^2, eps=1e-8
        const float qB = fmaxf(phB * psB, 1e-16f);
        const float cA = pdA * __builtin_amdgcn_rsqf(qA);
        const float cB = pdB * __builtin_amdgcn_rsqf(qB);
        const float aaA = 1.0f - cA;  // h_new = clip(h*(1-c) + s)
        const float aaB = 1.0f - cB;
        const unsigned mwA =
            (unsigned)__builtin_amdgcn_readlane((int)mbitsA, lbase + T);
        const unsigned mwB =
            (unsigned)__builtin_amdgcn_readlane((int)mbitsB, lbase + T);
        if ((mwA >> msh) & 1u) {
          const v2f av = v2f{aaA, aaA};
#pragma unroll
          for (int q = 0; q < 8; ++q) {
            v2f t = pk_fma(hA[q], av, sa[q]);
            hA[q].x = __builtin_amdgcn_fmed3f(t.x, -1.0f, 1.0f);
            hA[q].y = __builtin_amdgcn_fmed3f(t.y, -1.0f, 1.0f);
          }
        }
        if ((mwB >> msh) & 1u) {
          const v2f av = v2f{aaB, aaB};
#pragma unroll
          for (int q = 0; q < 8; ++q) {
            v2f t = pk_fma(hB[q], av, sb[q]);
            hB[q].x = __builtin_amdgcn_fmed3f(t.x, -1.0f, 1.0f);
            hB[q].y = __builtin_amdgcn_fmed3f(t.y, -1.0f, 1.0f);
          }
        }
      };
      step(ic<0>{}); step(ic<1>{}); step(ic<2>{}); step(ic<3>{});
      step(ic<4>{}); step(ic<5>{}); step(ic<6>{}); step(ic<7>{});
      asm volatile("s_barrier" ::: "memory");  // window g done
    }

    asm volatile("s_waitcnt vmcnt(0) lgkmcnt(0)" ::: "memory");
    float* orA = out + bA * NH + 4 * l;
    float* orB = out + bB * NH + 4 * l;
#pragma unroll
    for (int m = 0; m < 4; ++m) {
      float4 v;
      v.x = hA[2 * m].x; v.y = hA[2 * m].y;
      v.z = hA[2 * m + 1].x; v.w = hA[2 * m + 1].y;
      *(float4*)(orA + 256 * m) = v;
    }
#pragma unroll
    for (int m = 0; m < 4; ++m) {
      float4 v;
      v.x = hB[2 * m].x; v.y = hB[2 * m].y;
      v.z = hB[2 * m + 1].x; v.w = hB[2 * m + 1].y;
      *(float4*)(orB + 256 * m) = v;
    }
  } else {
    // ============================ PRODUCERS ===========================
    // 64 chunks per window (A: 0..31, B: 32..63). Chunk c (within batch) =
    // rows 32c..32c+31 x 8 steps. Lane l: row 32c+(l>>1), steps 4(l&1)+j.
    // Load: p = pb + (32c+(l>>1))*512 + 4(l&1) + 8*T_ floats (16B/lane).
    // LDS byte = batchsel + parity*BUFB + (4(l&1)+j)*4112 + 4*(32c+(l>>1))
    //   = wbase + batchsel + parity + j*4112 + 128c.
    // Banks: (16(l&1) + (l>>1)) mod 32 -> 2 lanes/bank (free minimum).
    const float* pbA = seq + (size_t)bA * NH * NS + (l >> 1) * 512 +
                       (l & 1) * 4;
    const float* pbB = seq + (size_t)bB * NH * NS + (l >> 1) * 512 +
                       (l & 1) * 4;
    const unsigned wbase =
        lb + 16448u * (unsigned)(l & 1) + 4u * (unsigned)(l >> 1);
    const int cb = w - 1;  // 0,1,2

    v4f ring[22];
#define STAGE(T_)                                                         \
    do {                                                                  \
      const int to_ = 8 * (T_);                                           \
      const unsigned po_ = ((T_) & 1) ? BUFB : 0u;                        \
      _Pragma("unroll") for (int k = 0; k < 22; ++k) {                    \
        const int cc = 3 * k + cb;                                        \
        if (cc < 64) {                                                    \
          const float* p_ = ((cc < 32) ? (pbA + cc * 16384)               \
                                       : (pbB + (cc - 32) * 16384)) +     \
                            to_;                                          \
          GLD4(ring[k], p_);                                              \
        }                                                                 \
      }                                                                   \
      asm volatile("s_waitcnt vmcnt(0)" ::: "memory");                    \
      _Pragma("unroll") for (int k = 0; k < 22; ++k) {                    \
        const int cc = 3 * k + cb;                                        \
        if (cc < 64) {                                                    \
          const unsigned a_ = wbase + po_ +                               \
              ((cc < 32) ? 0u : 2u * BUFB) + 128u * (unsigned)(cc & 31);  \
          dsw32<0 * 4112>(a_, ring[k][0]);                                \
          dsw32<1 * 4112>(a_, ring[k][1]);                                \
          dsw32<2 * 4112>(a_, ring[k][2]);                                \
          dsw32<3 * 4112>(a_, ring[k][3]);                                \
        }                                                                 \
      }                                                                   \
      asm volatile("s_waitcnt lgkmcnt(0)" ::: "memory");                  \
    } while (0)

    STAGE(0);                                // tiles 0 (A and B) -> parity 0
    asm volatile("s_barrier" ::: "memory");  // barrier #0

#pragma unroll 1
    for (int g = 0; g < 64; ++g) {
      if (g < 63) {
        STAGE(g + 1);                        // tiles g+1 -> parity (g+1)&1
      }
      asm volatile("s_barrier" ::: "memory");  // window g done
    }
#undef STAGE
  }
}

extern "C" void kernel_launch(void* const* d_in, const int* in_sizes, int n_in,
                              void* d_out, int out_size, void* d_ws,
                              size_t ws_size, hipStream_t stream) {
  const float* tree = (const float*)d_in[0];  // (64,1024)
  const float* seq = (const float*)d_in[1];   // (64,1024,512)
  const float* mask = (const float*)d_in[2];  // (64,512)
  float* out = (float*)d_out;                 // (64,1024)
  otsu_scan_kernel<<<dim3(NB), dim3(256), 0, stream>>>(tree, seq, mask, out);
}

// Round 11
// 274.189 us; speedup vs baseline: 1.4697x; 1.4697x over previous
//
#include <hip/hip_runtime.h>

// OrthogonalAddTSU: sequential scan over S steps, carry h:(B,H).
// Per step: cos = <h,s>/max(|h||s|,eps); h = clip(h + (s - h*cos)*m, -1, 1).
// B=64, H=1024, S=512.
//
// Round-15 = r13 (proven 129us) with a BRANCHLESS consumer step.
//  - r14 post-mortem: dual-batch-in-one-wave ran at IDENTICAL per-SIMD
//    issue density (56%) with ~2x instructions -> scheduler serialized the
//    two chains to cap register pressure (VGPR stayed 132). Wave-level ILP
//    via fat steps is dead; the lever is letting the scheduler overlap
//    ADJACENT steps of one thin chain.
//  - r13's per-step `if (act)` branches are scheduling barriers: step t's
//    butterfly->readlane->rsq stall (~200cy) can't overlap step t+1's
//    wait/extract/trees across basic blocks. This round: no branches.
//    Gating instead: aa = act ? (1-cos) : 1 ; s_g = s * act ;
//    h = clip(h*aa + s_g)  — identical to reference for both mask values
//    (m==0: clip(h)=h since h stays clipped). Cost: +8 pk_mul (gate) and
//    the reduce runs on masked steps too (~10%); benefit: the whole
//    16-step window is one straight-line DAG, only counted lgkmcnt waits
//    pin sval regs, all pure pk/DPP ops can cross step boundaries.
//  - Everything else byte-identical to r13: wave0 consumer / waves1-3
//    producers, stride 4112B (16B-aligned b128, 2-lanes/bank writes),
//    2-deep sval prefetch w/ counted lgkmcnt(4), 1 barrier per 16-step
//    window (33/33), all VMEM/LDS volatile asm, pk math pure asm.

#define NB 64
#define NH 1024
#define NS 512

#define STRF 1028              // step stride in floats (4112 B)
#define BUFF (16 * STRF)       // 16448 floats = 65792 B per tile buffer

typedef float v4f __attribute__((ext_vector_type(4)));
typedef float v2f __attribute__((ext_vector_type(2)));

template <int N> struct ic { static constexpr int value = N; };

template <int CTRL>
__device__ __forceinline__ float dpp_add(float x) {
  int s = __builtin_amdgcn_update_dpp(0, __builtin_bit_cast(int, x), CTRL, 0xf,
                                      0xf, true);
  return x + __builtin_bit_cast(float, s);
}

__device__ __forceinline__ float readlane_f(float v, int lane) {
  return __builtin_bit_cast(
      float, __builtin_amdgcn_readlane(__builtin_bit_cast(int, v), lane));
}

// 3 interleaved 6-stage butterflies; broadcast lane63 totals.
__device__ __forceinline__ void wave_red3(float& a, float& b, float& c) {
  a = dpp_add<0x111>(a); b = dpp_add<0x111>(b); c = dpp_add<0x111>(c);
  a = dpp_add<0x112>(a); b = dpp_add<0x112>(b); c = dpp_add<0x112>(c);
  a = dpp_add<0x114>(a); b = dpp_add<0x114>(b); c = dpp_add<0x114>(c);
  a = dpp_add<0x118>(a); b = dpp_add<0x118>(b); c = dpp_add<0x118>(c);
  a = dpp_add<0x142>(a); b = dpp_add<0x142>(b); c = dpp_add<0x142>(c);
  a = dpp_add<0x143>(a); b = dpp_add<0x143>(b); c = dpp_add<0x143>(c);
  a = readlane_f(a, 63);
  b = readlane_f(b, 63);
  c = readlane_f(c, 63);
}

#define GLD4(dst, p) \
  asm volatile("global_load_dwordx4 %0, %1, off" : "=v"(dst) : "v"(p))
#define GLD4O(dst, p, OFF) \
  asm volatile("global_load_dwordx4 %0, %1, off offset:" OFF \
               : "=v"(dst) : "v"(p))
#define GLD1(dst, p) \
  asm volatile("global_load_dword %0, %1, off" : "=v"(dst) : "v"(p))

template <int IMM>
__device__ __forceinline__ void dsr128(v4f& d, unsigned a) {
  asm volatile("ds_read_b128 %[d], %[a] offset:%[o]"
               : [d] "=v"(d)
               : [a] "v"(a), [o] "n"(IMM));
}
template <int IMM>
__device__ __forceinline__ void dsw32(unsigned a, float v) {
  asm volatile("ds_write_b32 %[a], %[v] offset:%[o]" ::[a] "v"(a), [v] "v"(v),
               [o] "n"(IMM));
}

// Packed fp32 math (pure: compiler may schedule freely; real dataflow).
__device__ __forceinline__ v2f pk_fma(v2f a, v2f b, v2f c) {
  v2f d;
  asm("v_pk_fma_f32 %0, %1, %2, %3" : "=v"(d) : "v"(a), "v"(b), "v"(c));
  return d;
}
__device__ __forceinline__ v2f pk_mul(v2f a, v2f b) {
  v2f d;
  asm("v_pk_mul_f32 %0, %1, %2" : "=v"(d) : "v"(a), "v"(b));
  return d;
}
__device__ __forceinline__ v2f pk_add(v2f a, v2f b) {
  v2f d;
  asm("v_pk_add_f32 %0, %1, %2" : "=v"(d) : "v"(a), "v"(b));
  return d;
}

#define LGK4SV(sv)                                                    \
  asm volatile("s_waitcnt lgkmcnt(4)"                                 \
               : "+v"((sv)[0]), "+v"((sv)[1]), "+v"((sv)[2]),         \
                 "+v"((sv)[3]))
#define LGK0SV(sv)                                                    \
  asm volatile("s_waitcnt lgkmcnt(0)"                                 \
               : "+v"((sv)[0]), "+v"((sv)[1]), "+v"((sv)[2]),         \
                 "+v"((sv)[3]))

__global__ __launch_bounds__(256, 1) void otsu_scan_kernel(
    const float* __restrict__ tree,   // (B,H)
    const float* __restrict__ seq,    // (B,H,S)
    const float* __restrict__ mask,   // (B,S)
    float* __restrict__ out) {        // (B,H)
  __shared__ float lds[2 * BUFF];  // 131584 B < 160 KiB
  const int b = blockIdx.x;
  const int tid = threadIdx.x;
  const int w = tid >> 6;   // wave 0..3 (wave-uniform)
  const int l = tid & 63;   // lane
  const unsigned lb = (unsigned)(unsigned long long)(&lds[0]);

  if (w == 0) {
    // ============================ CONSUMER ============================
    // lane l owns h[4l + 256m + {0..3}], m=0..3 -> 8 float2 pairs.
    const float* hrow = tree + b * NH + 4 * l;
    v4f hv0, hv1, hv2, hv3;
    GLD4(hv0, hrow);
    GLD4O(hv1, hrow, "1024");
    GLD4O(hv2, hrow, "2048");
    GLD4O(hv3, hrow, "3072");
    float m8[8];
    {
      const float* mp = mask + b * NS + l;
#pragma unroll
      for (int i = 0; i < 8; ++i) GLD1(m8[i], mp + 64 * i);
    }
    asm volatile("s_waitcnt vmcnt(0)"
                 : "+v"(hv0), "+v"(hv1), "+v"(hv2), "+v"(hv3), "+v"(m8[0]),
                   "+v"(m8[1]), "+v"(m8[2]), "+v"(m8[3]), "+v"(m8[4]),
                   "+v"(m8[5]), "+v"(m8[6]), "+v"(m8[7]));

    v2f h2[8];
    h2[0] = v2f{hv0[0], hv0[1]}; h2[1] = v2f{hv0[2], hv0[3]};
    h2[2] = v2f{hv1[0], hv1[1]}; h2[3] = v2f{hv1[2], hv1[3]};
    h2[4] = v2f{hv2[0], hv2[1]}; h2[5] = v2f{hv2[2], hv2[3]};
    h2[6] = v2f{hv3[0], hv3[1]}; h2[7] = v2f{hv3[2], hv3[3]};

    unsigned mbits = 0u;
#pragma unroll
    for (int i = 0; i < 8; ++i)
      if (m8[i] != 0.0f) mbits |= (1u << i);

    // t==0, m==0: clip still applies (loop leaves h unchanged when m==0)
    if (!(__builtin_amdgcn_readlane((int)mbits, 0) & 1)) {
#pragma unroll
      for (int p = 0; p < 8; ++p) {
        h2[p].x = __builtin_amdgcn_fmed3f(h2[p].x, -1.0f, 1.0f);
        h2[p].y = __builtin_amdgcn_fmed3f(h2[p].y, -1.0f, 1.0f);
      }
    }

    const unsigned rb0 = lb + 16u * (unsigned)l;
    v4f sval[3][4];

    asm volatile("s_barrier" ::: "memory");  // barrier #0: tile 0 staged

#pragma unroll 1
    for (int g = 0; g < 32; ++g) {
      const int lbase = (16 * g) & 63;
      const int msh = g >> 2;
      const unsigned rbuf = rb0 + ((g & 1) ? (unsigned)(BUFF * 4) : 0u);

      // --- window preamble: issue steps 0,1 (8 b128); wait step 0 ---
      dsr128<0 * 4112 + 0>(sval[0][0], rbuf);
      dsr128<0 * 4112 + 1024>(sval[0][1], rbuf);
      dsr128<0 * 4112 + 2048>(sval[0][2], rbuf);
      dsr128<0 * 4112 + 3072>(sval[0][3], rbuf);
      dsr128<1 * 4112 + 0>(sval[1][0], rbuf);
      dsr128<1 * 4112 + 1024>(sval[1][1], rbuf);
      dsr128<1 * 4112 + 2048>(sval[1][2], rbuf);
      dsr128<1 * 4112 + 3072>(sval[1][3], rbuf);
      LGK4SV(sval[0]);

      auto step = [&](auto sc) {
        constexpr int T = decltype(sc)::value;
        if constexpr (T >= 1 && T <= 14) LGK4SV(sval[T % 3]);
        else if constexpr (T == 15) LGK0SV(sval[0]);
        if constexpr (T <= 13) {  // prefetch step T+2 (2-deep)
          dsr128<(T + 2) * 4112 + 0>(sval[(T + 2) % 3][0], rbuf);
          dsr128<(T + 2) * 4112 + 1024>(sval[(T + 2) % 3][1], rbuf);
          dsr128<(T + 2) * 4112 + 2048>(sval[(T + 2) % 3][2], rbuf);
          dsr128<(T + 2) * 4112 + 3072>(sval[(T + 2) % 3][3], rbuf);
        }
        // wave-uniform gates (no branch: whole step is straight-line)
        const unsigned mw =
            (unsigned)__builtin_amdgcn_readlane((int)mbits, lbase + T);
        const bool act = (mw >> msh) & 1u;
        const float gf = act ? 1.0f : 0.0f;
        const v4f s0 = sval[T % 3][0], s1 = sval[T % 3][1],
                  s2 = sval[T % 3][2], s3 = sval[T % 3][3];
        v2f sp[8];
        sp[0] = v2f{s0[0], s0[1]}; sp[1] = v2f{s0[2], s0[3]};
        sp[2] = v2f{s1[0], s1[1]}; sp[3] = v2f{s1[2], s1[3]};
        sp[4] = v2f{s2[0], s2[1]}; sp[5] = v2f{s2[2], s2[3]};
        sp[6] = v2f{s3[0], s3[1]}; sp[7] = v2f{s3[2], s3[3]};
        v2f a0 = pk_mul(h2[0], sp[0]), a1 = pk_mul(h2[1], sp[1]);
        v2f a2 = pk_mul(h2[2], sp[2]), a3 = pk_mul(h2[3], sp[3]);
        v2f b0 = pk_mul(h2[0], h2[0]), b1 = pk_mul(h2[1], h2[1]);
        v2f b2 = pk_mul(h2[2], h2[2]), b3 = pk_mul(h2[3], h2[3]);
        v2f c0 = pk_mul(sp[0], sp[0]), c1 = pk_mul(sp[1], sp[1]);
        v2f c2 = pk_mul(sp[2], sp[2]), c3 = pk_mul(sp[3], sp[3]);
        a0 = pk_fma(h2[4], sp[4], a0); a1 = pk_fma(h2[5], sp[5], a1);
        a2 = pk_fma(h2[6], sp[6], a2); a3 = pk_fma(h2[7], sp[7], a3);
        b0 = pk_fma(h2[4], h2[4], b0); b1 = pk_fma(h2[5], h2[5], b1);
        b2 = pk_fma(h2[6], h2[6], b2); b3 = pk_fma(h2[7], h2[7], b3);
        c0 = pk_fma(sp[4], sp[4], c0); c1 = pk_fma(sp[5], sp[5], c1);
        c2 = pk_fma(sp[6], sp[6], c2); c3 = pk_fma(sp[7], sp[7], c3);
        v2f A = pk_add(pk_add(a0, a1), pk_add(a2, a3));
        v2f Bv = pk_add(pk_add(b0, b1), pk_add(b2, b3));
        v2f C = pk_add(pk_add(c0, c1), pk_add(c2, c3));
        float pd = A.x + A.y, ph = Bv.x + Bv.y, ps = C.x + C.y;
        wave_red3(pd, ph, ps);
        const float p = fmaxf(ph * ps, 1e-16f);  // denom^2, eps=1e-8
        const float cc = pd * __builtin_amdgcn_rsqf(p);
        // gated update: act -> clip(h*(1-c) + s); !act -> clip(h*1+0)=h
        const float aa = act ? (1.0f - cc) : 1.0f;
        const v2f av = v2f{aa, aa};
        const v2f gv = v2f{gf, gf};
#pragma unroll
        for (int q = 0; q < 8; ++q) {
          const v2f sg = pk_mul(sp[q], gv);
          const v2f t = pk_fma(h2[q], av, sg);
          h2[q].x = __builtin_amdgcn_fmed3f(t.x, -1.0f, 1.0f);
          h2[q].y = __builtin_amdgcn_fmed3f(t.y, -1.0f, 1.0f);
        }
      };
      step(ic<0>{});  step(ic<1>{});  step(ic<2>{});  step(ic<3>{});
      step(ic<4>{});  step(ic<5>{});  step(ic<6>{});  step(ic<7>{});
      step(ic<8>{});  step(ic<9>{});  step(ic<10>{}); step(ic<11>{});
      step(ic<12>{}); step(ic<13>{}); step(ic<14>{}); step(ic<15>{});
      asm volatile("s_barrier" ::: "memory");  // window g done
    }

    asm volatile("s_waitcnt vmcnt(0) lgkmcnt(0)" ::: "memory");
    float* orow = out + b * NH + 4 * l;
#pragma unroll
    for (int m = 0; m < 4; ++m) {
      float4 v;
      v.x = h2[2 * m].x;
      v.y = h2[2 * m].y;
      v.z = h2[2 * m + 1].x;
      v.w = h2[2 * m + 1].y;
      *(float4*)(orow + 256 * m) = v;
    }
  } else {
    // ============================ PRODUCERS ===========================
    // Wave w stages chunks c = 3k + (w-1), k=0..21, c<64. Chunk c = rows
    // 16c..16c+15 x 16 steps. Lane l: row 16c+(l>>2), steps 4(l&3)+j.
    // LDS byte(step t,row r) = bsel + t*4112 + 4r ->
    //   wpb = 16448(l&3) + 4(l>>2); write j at wpb + j*4112 + 64c.
    // Banks: (16(l&3)+(l>>2)) mod 32 -> 2 lanes/bank (free wave64 minimum).
    const float* pbase = seq + (size_t)b * NH * NS + (l >> 2) * 512 +
                         (l & 3) * 4;
    const unsigned wpb =
        lb + 16448u * (unsigned)(l & 3) + 4u * (unsigned)(l >> 2);
    const int cb = w - 1;  // 0,1,2

    v4f ring[22];
    // stage(tile t, bufsel): all loads -> vmcnt(0) -> all writes -> lgkm(0)
#define STAGE(T_, BSEL_)                                                  \
    do {                                                                  \
      _Pragma("unroll") for (int k = 0; k < 22; ++k) {                    \
        const int c = 3 * k + cb;                                         \
        if (c < 64) {                                                     \
          const float* p_ = pbase + c * 8192 + (T_) * 16;                 \
          GLD4(ring[k], p_);                                              \
        }                                                                 \
      }                                                                   \
      asm volatile("s_waitcnt vmcnt(0)" ::: "memory");                    \
      _Pragma("unroll") for (int k = 0; k < 22; ++k) {                    \
        const int c = 3 * k + cb;                                         \
        if (c < 64) {                                                     \
          const unsigned a_ = wpb + (BSEL_) + 64u * (unsigned)c;          \
          dsw32<0 * 4112>(a_, ring[k][0]);                                \
          dsw32<1 * 4112>(a_, ring[k][1]);                                \
          dsw32<2 * 4112>(a_, ring[k][2]);                                \
          dsw32<3 * 4112>(a_, ring[k][3]);                                \
        }                                                                 \
      }                                                                   \
      asm volatile("s_waitcnt lgkmcnt(0)" ::: "memory");                  \
    } while (0)

    STAGE(0, 0u);                            // tile 0 -> buf0
    asm volatile("s_barrier" ::: "memory");  // barrier #0

#pragma unroll 1
    for (int g = 0; g < 32; ++g) {
      if (g < 31) {
        const unsigned bsel = ((g + 1) & 1) ? (unsigned)(BUFF * 4) : 0u;
        STAGE(g + 1, bsel);                  // tile g+1 -> buf (g+1)&1
      }
      asm volatile("s_barrier" ::: "memory");  // window g done
    }
#undef STAGE
  }
}

extern "C" void kernel_launch(void* const* d_in, const int* in_sizes, int n_in,
                              void* d_out, int out_size, void* d_ws,
                              size_t ws_size, hipStream_t stream) {
  const float* tree = (const float*)d_in[0];  // (64,1024)
  const float* seq = (const float*)d_in[1];   // (64,1024,512)
  const float* mask = (const float*)d_in[2];  // (64,512)
  float* out = (float*)d_out;                 // (64,1024)
  otsu_scan_kernel<<<dim3(NB), dim3(64 * 4), 0, stream>>>(tree, seq, mask,
                                                          out);
}